// Round 1
// baseline (4751.850 us; speedup 1.0000x reference)
//
#include <hip/hip_runtime.h>

typedef unsigned short u16;
typedef unsigned long long u64;
typedef short bf16x8 __attribute__((ext_vector_type(8)));
typedef float f32x4 __attribute__((ext_vector_type(4)));

#define B_ 256
#define T_ 512
#define I_ 64
#define H_ 512
#define RING 32

// ---------------- ws layout (bytes) ----------------
// Flags are per-(layer, ib, producer-jn, producer-wave): F[ib][jn][w] u32.
//   F0: L0 h1 flags (stored by L0 wave after its own vmcnt(0) drain).
//       Polled by L0 (own recurrence, target t) AND L1 (input, target t+1).
//   F2: L1 h2 flags (own recurrence).
//   F3: L1 ring-consumed credits (per L1 block, wave), polled by L0 for ring reuse.
// Consumer wave cw of any block polls exactly one 128B line: [ib][8cw..8cw+8][0..4].
// h1 ring is the ONLY L0 h buffer (recurrent reads slot (t-1)&31; L1 reads slot t&31).
// Layout A-fragment-coalesced: [slot][k8=k/8][row 0..255][8 k-elems] bf16.
#define OFF_F0    0u
#define OFF_F2    4096u
#define OFF_F3    8192u
#define OFF_B0    12288u       // 2048 f32
#define OFF_B1    20480u       // 2048 f32
#define OFF_WIH0  28672u       // 2048x64 bf16
#define OFF_WHH0  290816u      // 2048x512 bf16
#define OFF_WIH1  2387968u     // 2048x512 bf16
#define OFF_WHH1  4485120u     // 2048x512 bf16
#define OFF_HX1   6582272u     // 2 x [64][256][8] bf16 (L1 own recurrent, parity)
#define OFF_H1R   7106560u     // RING x [64][256][8] bf16 ring (L0 out = L1 in + L0 rec)
#define WS_NEEDED 15495168u

#define AQ __ATOMIC_RELAXED
#define SC __HIP_MEMORY_SCOPE_AGENT

static __device__ __forceinline__ u16 f2b(float f) {
  union { float f; unsigned u; } v; v.f = f;
  unsigned r = (v.u + 0x7FFFu + ((v.u >> 16) & 1u)) >> 16;
  return (u16)r;
}
static __device__ __forceinline__ float sigm(float x) { return 1.f / (1.f + __expf(-x)); }
static __device__ __forceinline__ float tanh_(float x) { return 1.f - 2.f / (__expf(2.f * x) + 1.f); }

// ---------------- prep: bf16 weights, bias sums, flag zero, out=bfc ----------------
__global__ void prep_kernel(const float* __restrict__ Wih0, const float* __restrict__ Whh0,
                            const float* __restrict__ bih0, const float* __restrict__ bhh0,
                            const float* __restrict__ Wih1, const float* __restrict__ Whh1,
                            const float* __restrict__ bih1, const float* __restrict__ bhh1,
                            const float* __restrict__ bfc, float* __restrict__ out,
                            char* __restrict__ ws) {
  unsigned* flags = (unsigned*)(ws + OFF_F0);  // F0,F2,F3 contiguous: 3072 u32
  float* b0 = (float*)(ws + OFF_B0);
  float* b1 = (float*)(ws + OFF_B1);
  u16* wih0b = (u16*)(ws + OFF_WIH0);
  u16* whh0b = (u16*)(ws + OFF_WHH0);
  u16* wih1b = (u16*)(ws + OFF_WIH1);
  u16* whh1b = (u16*)(ws + OFF_WHH1);

  long long i = (long long)blockIdx.x * 256 + threadIdx.x;
  if (i < 3072) { __hip_atomic_store(&flags[i], 0u, AQ, SC); return; }
  i -= 3072;
  if (i < 256) { out[i] = bfc[0]; return; }   // FC bias; L1 atomicAdds partials
  i -= 256;
  if (i < 2048) { b0[i] = bih0[i] + bhh0[i]; return; }
  i -= 2048;
  if (i < 2048) { b1[i] = bih1[i] + bhh1[i]; return; }
  i -= 2048;
  if (i < 131072) { wih0b[i] = f2b(Wih0[i]); return; }
  i -= 131072;
  if (i < 1048576) { whh0b[i] = f2b(Whh0[i]); return; }
  i -= 1048576;
  if (i < 1048576) { wih1b[i] = f2b(Wih1[i]); return; }
  i -= 1048576;
  if (i < 1048576) { whh1b[i] = f2b(Whh1[i]); return; }
}

// ---------------- fused 2-layer pipelined LSTM ----------------
// 512 blocks co-resident (2/CU): 0-255 = layer0, 256-511 = layer1 (lag 1 step).
// Block (ib=bx>>5, jn=bx&31): 32 batch rows x 16 h-cols; 4 waves K-split; Whh in regs.
// Sync protocol (per step): ONE __syncthreads (before elemwise, Gp_s double-buffered).
//   producer wave: elemwise stores -> s_waitcnt vmcnt(0) -> its own 4B flag.
//   consumer wave: polls only its K-slice's 8 producers x 4 wave-flags (one 128B line).
template <bool IS_L0>
__device__ __forceinline__ void lstm_body(
    int bx,
    const float* __restrict__ x,      // L0: [B,T,64]
    const u16* __restrict__ Wib,      // bf16: L0 [2048][64], L1 [2048][512]
    const u16* __restrict__ Whb,      // bf16 [2048][512]
    const float* __restrict__ bias,   // [2048]
    unsigned* __restrict__ hx32,      // L1 only: own recurrent parity buffer (u32 view)
    u16* __restrict__ h1ring,         // ring [RING][64][256][8] bf16
    const float* __restrict__ Wfc, float* __restrict__ out,
    unsigned* __restrict__ Fown,      // flags this layer stores after h (L0: F0, L1: F2)
    unsigned* __restrict__ Fin,       // L1 only: input-h flags (= F0)
    unsigned* __restrict__ Fcr,       // credits F3 (L0 polls, L1 stores)
    float* __restrict__ Gp_s)         // [2][4*32][68] partial-sum double buffer
{
  const int tid = threadIdx.x;
  const int wv = tid >> 6;
  const int lane = tid & 63;
  const int quad = lane >> 4;
  const int l15 = lane & 15;
  const int jn = bx & 31;
  const int ib = bx >> 5;

  // ---- preload B fragments (lane: n=l15, k=quad*8+j); wave owns ksteps wv*4..wv*4+3
  bf16x8 Bh[4][4];
#pragma unroll
  for (int r = 0; r < 4; ++r)
#pragma unroll
    for (int nt = 0; nt < 4; ++nt)
      Bh[r][nt] = *(const bf16x8*)&Whb[(size_t)(nt * 512 + jn * 16 + l15) * 512 +
                                       (wv * 4 + r) * 32 + quad * 8];
  bf16x8 Bx[4][4];  // L1 input weights (full K=512 split)
  bf16x8 Bx0[4];    // L0 input weights (waves 0,1; K-half = wv)
  if constexpr (IS_L0) {
    if (wv < 2) {
#pragma unroll
      for (int nt = 0; nt < 4; ++nt)
        Bx0[nt] = *(const bf16x8*)&Wib[(size_t)(nt * 512 + jn * 16 + l15) * 64 +
                                       wv * 32 + quad * 8];
    }
  } else {
#pragma unroll
    for (int r = 0; r < 4; ++r)
#pragma unroll
      for (int nt = 0; nt < 4; ++nt)
        Bx[r][nt] = *(const bf16x8*)&Wib[(size_t)(nt * 512 + jn * 16 + l15) * 512 +
                                         (wv * 4 + r) * 32 + quad * 8];
  }

  const int erow = tid >> 3;     // elementwise: batch row 0..31 (wave w owns rows 8w..8w+8)
  const int ecp = tid & 7;       // col pair
  float bias2[4][2];
#pragma unroll
  for (int g = 0; g < 4; ++g) {
    bias2[g][0] = bias[g * 512 + jn * 16 + 2 * ecp];
    bias2[g][1] = bias[g * 512 + jn * 16 + 2 * ecp + 1];
  }
  float cst2[2] = {0.f, 0.f};
  const f32x4 zf = {0.f, 0.f, 0.f, 0.f};

  // transposed-layout store offset (u32 units): hg -> k8 = hg>>3, elem pair = ecp&3
  const int bg = ib * 32 + erow;
  const int hg = jn * 16 + 2 * ecp;
  const unsigned stoff = (unsigned)(((hg >> 3) * 256 + bg) * 4 + (ecp & 3));

  // flag addressing (u32 units)
  const int fown_idx = ib * 128 + jn * 4 + wv;              // this wave's own slot
  const unsigned* __restrict__ pollOwn = Fown + ib * 128 + wv * 32;  // 8 prods x 4 waves
  const unsigned* __restrict__ pollIn  = IS_L0 ? (const unsigned*)nullptr
                                               : Fin + ib * 128 + wv * 32;
  const unsigned* __restrict__ pollCr  = Fcr + ib * 128 + (jn >> 3); // +4*jn' per lane

  for (int t = 0; t < T_; ++t) {
    f32x4 acc[2][4];
#pragma unroll
    for (int mt = 0; mt < 2; ++mt)
#pragma unroll
      for (int nt = 0; nt < 4; ++nt) acc[mt][nt] = zf;

    if constexpr (IS_L0) {
      // issue x(t) loads to registers BEFORE the poll (latency hides under the spin)
      float4 xa, xb, xc, xd;
      if (wv < 2) {
        const float* xp = x + ((size_t)(ib * 32 + l15) * T_ + t) * 64 + wv * 32 + quad * 8;
        const float* xq = xp + (size_t)16 * T_ * 64;
        xa = *(const float4*)xp;  xb = *(const float4*)(xp + 4);
        xc = *(const float4*)xq;  xd = *(const float4*)(xq + 4);
      }
      // per-wave poll: own clique flags >= t; wave0 lanes>=32 also poll ring credits
      if (t) {
        const unsigned tgtF = (unsigned)t;
        const bool cchk = (wv == 0) && (t >= RING);
        const unsigned tgtC = cchk ? (unsigned)(t - (RING - 1)) : 0u;
        for (;;) {
          unsigned vv, tg;
          if (cchk && lane >= 32) {
            vv = __hip_atomic_load(&pollCr[(lane - 32) * 4], AQ, SC); tg = tgtC;
          } else {
            vv = __hip_atomic_load(&pollOwn[lane & 31], AQ, SC); tg = tgtF;
          }
          if (!__any(vv < tg)) break;
        }
      }
      // input GEMM (registers only, no LDS)
      if (wv < 2) {
        union { unsigned u[4]; bf16x8 v; } P0, P1;
        P0.u[0] = (unsigned)f2b(xa.x) | ((unsigned)f2b(xa.y) << 16);
        P0.u[1] = (unsigned)f2b(xa.z) | ((unsigned)f2b(xa.w) << 16);
        P0.u[2] = (unsigned)f2b(xb.x) | ((unsigned)f2b(xb.y) << 16);
        P0.u[3] = (unsigned)f2b(xb.z) | ((unsigned)f2b(xb.w) << 16);
        P1.u[0] = (unsigned)f2b(xc.x) | ((unsigned)f2b(xc.y) << 16);
        P1.u[1] = (unsigned)f2b(xc.z) | ((unsigned)f2b(xc.w) << 16);
        P1.u[2] = (unsigned)f2b(xd.x) | ((unsigned)f2b(xd.y) << 16);
        P1.u[3] = (unsigned)f2b(xd.z) | ((unsigned)f2b(xd.w) << 16);
#pragma unroll
        for (int nt = 0; nt < 4; ++nt) {
          acc[0][nt] = __builtin_amdgcn_mfma_f32_16x16x32_bf16(P0.v, Bx0[nt], acc[0][nt], 0, 0, 0);
          acc[1][nt] = __builtin_amdgcn_mfma_f32_16x16x32_bf16(P1.v, Bx0[nt], acc[1][nt], 0, 0, 0);
        }
      }
    } else {
      // per-wave poll: lanes<32 input h1(t) ready (F0 >= t+1); lanes>=32 own rec (F2 >= t)
      {
        const unsigned tgtI = (unsigned)(t + 1);
        const unsigned tgtR = (unsigned)t;
        for (;;) {
          unsigned vv, tg;
          if (lane < 32) { vv = __hip_atomic_load(&pollIn[lane], AQ, SC); tg = tgtI; }
          else           { vv = __hip_atomic_load(&pollOwn[lane - 32], AQ, SC); tg = tgtR; }
          if (!__any(vv < tg)) break;
        }
      }
      // input GEMM from ring slot t&(RING-1)
      const u64* hq1 = (const u64*)h1ring + (size_t)(t & (RING - 1)) * (B_ * H_ / 4);
#pragma unroll
      for (int r = 0; r < 4; ++r) {
        int ks = wv * 4 + r;
        bf16x8 af[2];
#pragma unroll
        for (int mt = 0; mt < 2; ++mt) {
          const u64* p = hq1 + (size_t)((ks * 4 + quad) * 256 + ib * 32 + mt * 16 + l15) * 2;
          union { u64 q[2]; bf16x8 v; } u;
          u.q[0] = __hip_atomic_load(p, AQ, SC);
          u.q[1] = __hip_atomic_load(p + 1, AQ, SC);
          af[mt] = u.v;
        }
#pragma unroll
        for (int nt = 0; nt < 4; ++nt) {
          acc[0][nt] = __builtin_amdgcn_mfma_f32_16x16x32_bf16(af[0], Bx[r][nt], acc[0][nt], 0, 0, 0);
          acc[1][nt] = __builtin_amdgcn_mfma_f32_16x16x32_bf16(af[1], Bx[r][nt], acc[1][nt], 0, 0, 0);
        }
      }
    }

    // ---- recurrent GEMM: L0 reads the ring (slot t-1), L1 its parity buffer
    if (t) {
      const u64* hq;
      if constexpr (IS_L0)
        hq = (const u64*)h1ring + (size_t)((t - 1) & (RING - 1)) * (B_ * H_ / 4);
      else
        hq = (const u64*)hx32 + (size_t)(t & 1) * (B_ * H_ / 4);
      bf16x8 af[4][2];
#pragma unroll
      for (int r = 0; r < 4; ++r) {
        int ks = wv * 4 + r;
#pragma unroll
        for (int mt = 0; mt < 2; ++mt) {
          const u64* p = hq + (size_t)((ks * 4 + quad) * 256 + ib * 32 + mt * 16 + l15) * 2;
          union { u64 q[2]; bf16x8 v; } u;
          u.q[0] = __hip_atomic_load(p, AQ, SC);
          u.q[1] = __hip_atomic_load(p + 1, AQ, SC);
          af[r][mt] = u.v;
        }
      }
#pragma unroll
      for (int r = 0; r < 4; ++r)
#pragma unroll
        for (int mt = 0; mt < 2; ++mt)
#pragma unroll
          for (int nt = 0; nt < 4; ++nt)
            acc[mt][nt] = __builtin_amdgcn_mfma_f32_16x16x32_bf16(af[r][mt], Bh[r][nt],
                                                                  acc[mt][nt], 0, 0, 0);
    }

    // ---- dump per-wave partials into double-buffered Gp (D: col=l15, row=quad*4+reg)
    float* __restrict__ Gp = Gp_s + (t & 1) * (4 * 32 * 68);
#pragma unroll
    for (int mt = 0; mt < 2; ++mt)
#pragma unroll
      for (int nt = 0; nt < 4; ++nt)
#pragma unroll
        for (int rr = 0; rr < 4; ++rr)
          Gp[(wv * 32 + mt * 16 + quad * 4 + rr) * 68 + nt * 16 + l15] = acc[mt][nt][rr];
    __syncthreads();   // the ONLY barrier per step

    // ---- elementwise: reduce partials, gates, c/h update, store h, per-wave flag
    {
      float pre[4][2];
#pragma unroll
      for (int g = 0; g < 4; ++g) {
        int c = g * 16 + 2 * ecp;
        float s0 = bias2[g][0], s1 = bias2[g][1];
#pragma unroll
        for (int w = 0; w < 4; ++w) {
          s0 += Gp[(w * 32 + erow) * 68 + c];
          s1 += Gp[(w * 32 + erow) * 68 + c + 1];
        }
        pre[g][0] = s0; pre[g][1] = s1;
      }
      float hv[2];
#pragma unroll
      for (int j = 0; j < 2; ++j) {
        float iv = sigm(pre[0][j]);
        float fv = sigm(pre[1][j]);
        float gv = tanh_(pre[2][j]);
        float ov = sigm(pre[3][j]);
        float cn = fv * cst2[j] + iv * gv;
        cst2[j] = cn;
        hv[j] = ov * tanh_(cn);
      }
      unsigned pack = (unsigned)f2b(hv[0]) | ((unsigned)f2b(hv[1]) << 16);
      if constexpr (IS_L0) {
        unsigned* ring32 = (unsigned*)h1ring;
        __hip_atomic_store(&ring32[(size_t)(t & (RING - 1)) * (B_ * H_ / 2) + stoff],
                           pack, AQ, SC);
      } else {
        __hip_atomic_store(&hx32[(size_t)((t + 1) & 1) * (B_ * H_ / 2) + stoff], pack, AQ, SC);
        if (t == T_ - 1) {
          float part = hv[0] * Wfc[hg] + hv[1] * Wfc[hg + 1];
          part += __shfl_down(part, 4, 8);
          part += __shfl_down(part, 2, 8);
          part += __shfl_down(part, 1, 8);
          if (ecp == 0) atomicAdd(&out[bg], part);
        }
      }
    }

    // ---- per-wave drain + flag (no barrier): this wave's h rows are now visible
    asm volatile("s_waitcnt vmcnt(0)" ::: "memory");
    if (lane == 0) {
      __hip_atomic_store(&Fown[fown_idx], (unsigned)(t + 1), AQ, SC);
      if constexpr (!IS_L0)   // ring credit: slot t consumed (x-loads long since retired)
        __hip_atomic_store(&Fcr[fown_idx], (unsigned)(t + 1), AQ, SC);
    }
  }
}

__global__ __launch_bounds__(256, 2) void lstm_fused(
    const float* __restrict__ x,
    const u16* __restrict__ wih0, const u16* __restrict__ whh0, const float* __restrict__ b0,
    const u16* __restrict__ wih1, const u16* __restrict__ whh1, const float* __restrict__ b1,
    unsigned* __restrict__ hx1, u16* __restrict__ h1ring,
    const float* __restrict__ Wfc, float* __restrict__ out,
    unsigned* __restrict__ f0, unsigned* __restrict__ f2, unsigned* __restrict__ f3)
{
  __shared__ __align__(16) float Gp_s[2 * 4 * 32 * 68];
  if (blockIdx.x < 256)
    lstm_body<true>(blockIdx.x, x, wih0, whh0, b0, (unsigned*)nullptr, h1ring,
                    (const float*)nullptr, (float*)nullptr, f0, (unsigned*)nullptr, f3, Gp_s);
  else
    lstm_body<false>(blockIdx.x - 256, (const float*)nullptr, wih1, whh1, b1, hx1, h1ring,
                     Wfc, out, f2, f0, f3, Gp_s);
}

extern "C" void kernel_launch(void* const* d_in, const int* in_sizes, int n_in,
                              void* d_out, int out_size, void* d_ws, size_t ws_size,
                              hipStream_t stream) {
  if (ws_size < (size_t)WS_NEEDED) return;

  const float* x    = (const float*)d_in[0];
  const float* Wih0 = (const float*)d_in[1];
  const float* Whh0 = (const float*)d_in[2];
  const float* bih0 = (const float*)d_in[3];
  const float* bhh0 = (const float*)d_in[4];
  const float* Wih1 = (const float*)d_in[5];
  const float* Whh1 = (const float*)d_in[6];
  const float* bih1 = (const float*)d_in[7];
  const float* bhh1 = (const float*)d_in[8];
  const float* Wfc  = (const float*)d_in[9];
  const float* bfc  = (const float*)d_in[10];

  char* ws = (char*)d_ws;
  unsigned* f0   = (unsigned*)(ws + OFF_F0);
  unsigned* f2   = (unsigned*)(ws + OFF_F2);
  unsigned* f3   = (unsigned*)(ws + OFF_F3);
  float* b0      = (float*)(ws + OFF_B0);
  float* b1      = (float*)(ws + OFF_B1);
  u16* wih0b     = (u16*)(ws + OFF_WIH0);
  u16* whh0b     = (u16*)(ws + OFF_WHH0);
  u16* wih1b     = (u16*)(ws + OFF_WIH1);
  u16* whh1b     = (u16*)(ws + OFF_WHH1);
  unsigned* hx1  = (unsigned*)(ws + OFF_HX1);
  u16* h1ring    = (u16*)(ws + OFF_H1R);
  float* out     = (float*)d_out;

  // prep: 3072 + 256 + 2048*2 + 131072 + 3*1048576 = 3,284,224 elements = 12829 blocks
  prep_kernel<<<12829, 256, 0, stream>>>(Wih0, Whh0, bih0, bhh0, Wih1, Whh1, bih1, bhh1,
                                         bfc, out, ws);

  lstm_fused<<<512, 256, 0, stream>>>(x, wih0b, whh0b, b0, wih1b, whh1b, b1,
                                      hx1, h1ring, Wfc, out, f0, f2, f3);
}

// Round 3
// 3835.727 us; speedup vs baseline: 1.2388x; 1.2388x over previous
//
#include <hip/hip_runtime.h>

typedef unsigned short u16;
typedef unsigned long long u64;
typedef short bf16x8 __attribute__((ext_vector_type(8)));
typedef float f32x4 __attribute__((ext_vector_type(4)));

#define B_ 256
#define T_ 512
#define I_ 64
#define H_ 512
#define RING 32

// ---------------- ws layout (bytes) ----------------
// CONSUMER-indexed private poll lines (the R0 lesson: 1 spinning reader per line).
// L0C[ib][jn][w][64 u32]: polled by L0 block (ib,jn) wave w.
//   slots 0-31  = clique rec flags: producer (jn'=8w+p, wave pw) at slot p*4+pw
//   slots 32-63 = ring credits (wave-0 line only): L1 block jn' at slot 32+jn'
// L1C[ib][jn][w][64 u32]: polled by L1 block (ib,jn) wave w.
//   slots 0-31  = h1-input flags from L0 (same slot mapping as above)
//   slots 32-63 = own rec flags from L1 producers at slot 32+p*4+pw
// Every slot has exactly ONE writer; every line exactly ONE polling wave.
// h1 ring is the only L0 h buffer (L0 rec reads slot (t-1)&31; L1 reads slot t&31).
// Ring layout A-fragment-coalesced: [slot][k8=k/8][row 0..255][8 k-elems] bf16.
#define OFF_L0C   0u           // 262144 B
#define OFF_L1C   262144u      // 262144 B
#define OFF_B0    524288u      // 2048 f32
#define OFF_B1    532480u      // 2048 f32
#define OFF_WIH0  540672u      // 2048x64 bf16
#define OFF_WHH0  802816u      // 2048x512 bf16
#define OFF_WIH1  2899968u     // 2048x512 bf16
#define OFF_WHH1  4997120u     // 2048x512 bf16
#define OFF_HX1   7094272u     // 2 x [64][256][8] bf16 (L1 own recurrent, parity)
#define OFF_H1R   7618560u     // RING x [64][256][8] bf16 ring
#define WS_NEEDED 16007168u

#define AQ __ATOMIC_RELAXED
#define SC __HIP_MEMORY_SCOPE_AGENT

static __device__ __forceinline__ u16 f2b(float f) {
  union { float f; unsigned u; } v; v.f = f;
  unsigned r = (v.u + 0x7FFFu + ((v.u >> 16) & 1u)) >> 16;
  return (u16)r;
}
static __device__ __forceinline__ float sigm(float x) { return 1.f / (1.f + __expf(-x)); }
static __device__ __forceinline__ float tanh_(float x) { return 1.f - 2.f / (__expf(2.f * x) + 1.f); }

// ---------------- prep: bf16 weights, bias sums, flag zero, out=bfc ----------------
__global__ void prep_kernel(const float* __restrict__ Wih0, const float* __restrict__ Whh0,
                            const float* __restrict__ bih0, const float* __restrict__ bhh0,
                            const float* __restrict__ Wih1, const float* __restrict__ Whh1,
                            const float* __restrict__ bih1, const float* __restrict__ bhh1,
                            const float* __restrict__ bfc, float* __restrict__ out,
                            char* __restrict__ ws) {
  unsigned* flags = (unsigned*)(ws + OFF_L0C);  // L0C+L1C contiguous: 131072 u32
  float* b0 = (float*)(ws + OFF_B0);
  float* b1 = (float*)(ws + OFF_B1);
  u16* wih0b = (u16*)(ws + OFF_WIH0);
  u16* whh0b = (u16*)(ws + OFF_WHH0);
  u16* wih1b = (u16*)(ws + OFF_WIH1);
  u16* whh1b = (u16*)(ws + OFF_WHH1);

  long long i = (long long)blockIdx.x * 256 + threadIdx.x;
  if (i < 131072) { __hip_atomic_store(&flags[i], 0u, AQ, SC); return; }
  i -= 131072;
  if (i < 256) { out[i] = bfc[0]; return; }   // FC bias; L1 atomicAdds partials
  i -= 256;
  if (i < 2048) { b0[i] = bih0[i] + bhh0[i]; return; }
  i -= 2048;
  if (i < 2048) { b1[i] = bih1[i] + bhh1[i]; return; }
  i -= 2048;
  if (i < 131072) { wih0b[i] = f2b(Wih0[i]); return; }
  i -= 131072;
  if (i < 1048576) { whh0b[i] = f2b(Whh0[i]); return; }
  i -= 1048576;
  if (i < 1048576) { wih1b[i] = f2b(Wih1[i]); return; }
  i -= 1048576;
  if (i < 1048576) { whh1b[i] = f2b(Whh1[i]); return; }
}

// ---------------- fused 2-layer pipelined LSTM ----------------
// 512 blocks co-resident (2/CU): 0-255 = layer0, 256-511 = layer1 (lag 1 step).
// Block (ib=bx>>5, jn=bx&31): 32 batch rows x 16 h-cols; 4 waves K-split; Whh in regs.
// Per step: poll (private line, 1 load/iter) -> GEMMs -> Gp dump -> ONE barrier ->
// elemwise -> per-wave vmcnt(0) drain -> single-scatter signal.
// WAR safety: union of the 4 waves' polls covers the whole clique, and the barrier
// sits between poll and the h/ring overwrite (verified-correct R1 argument).
template <bool IS_L0>
__device__ __forceinline__ void lstm_body(
    int bx,
    const float* __restrict__ x,      // L0: [B,T,64]
    const u16* __restrict__ Wib,      // bf16: L0 [2048][64], L1 [2048][512]
    const u16* __restrict__ Whb,      // bf16 [2048][512]
    const float* __restrict__ bias,   // [2048]
    unsigned* __restrict__ hx32,      // L1 only: own recurrent parity buffer (u32 view)
    u16* __restrict__ h1ring,         // ring [RING][64][256][8] bf16
    const float* __restrict__ Wfc, float* __restrict__ out,
    unsigned* __restrict__ L0C,       // L0 consumer poll lines
    unsigned* __restrict__ L1C,       // L1 consumer poll lines
    float* __restrict__ Gp_s)         // [2][4*32][68] partial-sum double buffer
{
  const int tid = threadIdx.x;
  const int wv = tid >> 6;
  const int lane = tid & 63;
  const int quad = lane >> 4;
  const int l15 = lane & 15;
  const int jn = bx & 31;
  const int ib = bx >> 5;

  // ---- preload B fragments (lane: n=l15, k=quad*8+j); wave owns ksteps wv*4..wv*4+3
  bf16x8 Bh[4][4];
#pragma unroll
  for (int r = 0; r < 4; ++r)
#pragma unroll
    for (int nt = 0; nt < 4; ++nt)
      Bh[r][nt] = *(const bf16x8*)&Whb[(size_t)(nt * 512 + jn * 16 + l15) * 512 +
                                       (wv * 4 + r) * 32 + quad * 8];
  bf16x8 Bx[4][4];  // L1 input weights (full K=512 split)
  bf16x8 Bx0[4];    // L0 input weights (waves 0,1; K-half = wv)
  if constexpr (IS_L0) {
    if (wv < 2) {
#pragma unroll
      for (int nt = 0; nt < 4; ++nt)
        Bx0[nt] = *(const bf16x8*)&Wib[(size_t)(nt * 512 + jn * 16 + l15) * 64 +
                                       wv * 32 + quad * 8];
    }
  } else {
#pragma unroll
    for (int r = 0; r < 4; ++r)
#pragma unroll
      for (int nt = 0; nt < 4; ++nt)
        Bx[r][nt] = *(const bf16x8*)&Wib[(size_t)(nt * 512 + jn * 16 + l15) * 512 +
                                         (wv * 4 + r) * 32 + quad * 8];
  }

  const int erow = tid >> 3;     // elementwise: batch row 0..31 (wave w owns rows 8w..8w+8)
  const int ecp = tid & 7;       // col pair
  float bias2[4][2];
#pragma unroll
  for (int g = 0; g < 4; ++g) {
    bias2[g][0] = bias[g * 512 + jn * 16 + 2 * ecp];
    bias2[g][1] = bias[g * 512 + jn * 16 + 2 * ecp + 1];
  }
  float cst2[2] = {0.f, 0.f};
  const f32x4 zf = {0.f, 0.f, 0.f, 0.f};

  // transposed-layout store offset (u32 units): hg -> k8 = hg>>3, elem pair = ecp&3
  const int bg = ib * 32 + erow;
  const int hg = jn * 16 + 2 * ecp;
  const unsigned stoff = (unsigned)(((hg >> 3) * 256 + bg) * 4 + (ecp & 3));

  // ---- poll line (private per wave) and signal address (one writer per slot)
  const unsigned* __restrict__ pollP =
      (IS_L0 ? L0C : L1C) + (((unsigned)(ib * 32 + jn) * 4 + wv) * 64 + lane);
  unsigned* sigPtr;
  if constexpr (IS_L0) {
    // lane<32: rec flag -> L0C line (ib, lane, jn>>3) slot (jn&7)*4+wv
    // lane>=32: input flag -> L1C line (ib, lane-32, jn>>3) same slot
    unsigned* base = (lane < 32) ? L0C : L1C;
    sigPtr = base + (((unsigned)(ib * 32 + (lane & 31)) * 4 + (jn >> 3)) * 64 +
                     (jn & 7) * 4 + wv);
  } else {
    // lane<32: rec flag -> L1C line (ib, lane, jn>>3) slot 32+(jn&7)*4+wv
    // lane 32..39: ring credit -> L0C line (ib, 8*wv+(lane-32), 0) slot 32+jn
    if (lane < 32)
      sigPtr = L1C + (((unsigned)(ib * 32 + lane) * 4 + (jn >> 3)) * 64 +
                      32 + (jn & 7) * 4 + wv);
    else
      sigPtr = L0C + (((unsigned)(ib * 32 + 8 * wv + (lane - 32)) * 4) * 64 + 32 + jn);
  }

  for (int t = 0; t < T_; ++t) {
    f32x4 acc[2][4];
#pragma unroll
    for (int mt = 0; mt < 2; ++mt)
#pragma unroll
      for (int nt = 0; nt < 4; ++nt) acc[mt][nt] = zf;

    if constexpr (IS_L0) {
      // issue x(t) loads to registers BEFORE the poll (latency hides under the spin)
      float4 xa, xb, xc, xd;
      if (wv < 2) {
        const float* xp = x + ((size_t)(ib * 32 + l15) * T_ + t) * 64 + wv * 32 + quad * 8;
        const float* xq = xp + (size_t)16 * T_ * 64;
        xa = *(const float4*)xp;  xb = *(const float4*)(xp + 4);
        xc = *(const float4*)xq;  xd = *(const float4*)(xq + 4);
      }
      // private-line poll: slots 0-31 rec flags >= t; slots 32-63 credits (wave0, t>=RING)
      if (t) {
        const unsigned tg = (lane < 32)
            ? (unsigned)t
            : ((wv == 0 && t >= RING) ? (unsigned)(t - (RING - 1)) : 0u);
        while (__any(__hip_atomic_load(pollP, AQ, SC) < tg)) {}
      }
      // input GEMM (registers only, no LDS)
      if (wv < 2) {
        union { unsigned u[4]; bf16x8 v; } P0, P1;
        P0.u[0] = (unsigned)f2b(xa.x) | ((unsigned)f2b(xa.y) << 16);
        P0.u[1] = (unsigned)f2b(xa.z) | ((unsigned)f2b(xa.w) << 16);
        P0.u[2] = (unsigned)f2b(xb.x) | ((unsigned)f2b(xb.y) << 16);
        P0.u[3] = (unsigned)f2b(xb.z) | ((unsigned)f2b(xb.w) << 16);
        P1.u[0] = (unsigned)f2b(xc.x) | ((unsigned)f2b(xc.y) << 16);
        P1.u[1] = (unsigned)f2b(xc.z) | ((unsigned)f2b(xc.w) << 16);
        P1.u[2] = (unsigned)f2b(xd.x) | ((unsigned)f2b(xd.y) << 16);
        P1.u[3] = (unsigned)f2b(xd.z) | ((unsigned)f2b(xd.w) << 16);
#pragma unroll
        for (int nt = 0; nt < 4; ++nt) {
          acc[0][nt] = __builtin_amdgcn_mfma_f32_16x16x32_bf16(P0.v, Bx0[nt], acc[0][nt], 0, 0, 0);
          acc[1][nt] = __builtin_amdgcn_mfma_f32_16x16x32_bf16(P1.v, Bx0[nt], acc[1][nt], 0, 0, 0);
        }
      }
    } else {
      // private-line poll: slots 0-31 h1(t) input flags >= t+1; slots 32-63 rec >= t
      {
        const unsigned tg = (lane < 32) ? (unsigned)(t + 1) : (unsigned)t;
        while (__any(__hip_atomic_load(pollP, AQ, SC) < tg)) {}
      }
      // input GEMM from ring slot t&(RING-1)
      const u64* hq1 = (const u64*)h1ring + (size_t)(t & (RING - 1)) * (B_ * H_ / 4);
#pragma unroll
      for (int r = 0; r < 4; ++r) {
        int ks = wv * 4 + r;
        bf16x8 af[2];
#pragma unroll
        for (int mt = 0; mt < 2; ++mt) {
          const u64* p = hq1 + (size_t)((ks * 4 + quad) * 256 + ib * 32 + mt * 16 + l15) * 2;
          union { u64 q[2]; bf16x8 v; } u;
          u.q[0] = __hip_atomic_load(p, AQ, SC);
          u.q[1] = __hip_atomic_load(p + 1, AQ, SC);
          af[mt] = u.v;
        }
#pragma unroll
        for (int nt = 0; nt < 4; ++nt) {
          acc[0][nt] = __builtin_amdgcn_mfma_f32_16x16x32_bf16(af[0], Bx[r][nt], acc[0][nt], 0, 0, 0);
          acc[1][nt] = __builtin_amdgcn_mfma_f32_16x16x32_bf16(af[1], Bx[r][nt], acc[1][nt], 0, 0, 0);
        }
      }
    }

    // ---- recurrent GEMM: L0 reads the ring (slot t-1), L1 its parity buffer
    if (t) {
      const u64* hq;
      if constexpr (IS_L0)
        hq = (const u64*)h1ring + (size_t)((t - 1) & (RING - 1)) * (B_ * H_ / 4);
      else
        hq = (const u64*)hx32 + (size_t)(t & 1) * (B_ * H_ / 4);
      bf16x8 af[4][2];
#pragma unroll
      for (int r = 0; r < 4; ++r) {
        int ks = wv * 4 + r;
#pragma unroll
        for (int mt = 0; mt < 2; ++mt) {
          const u64* p = hq + (size_t)((ks * 4 + quad) * 256 + ib * 32 + mt * 16 + l15) * 2;
          union { u64 q[2]; bf16x8 v; } u;
          u.q[0] = __hip_atomic_load(p, AQ, SC);
          u.q[1] = __hip_atomic_load(p + 1, AQ, SC);
          af[r][mt] = u.v;
        }
      }
#pragma unroll
      for (int r = 0; r < 4; ++r)
#pragma unroll
        for (int mt = 0; mt < 2; ++mt)
#pragma unroll
          for (int nt = 0; nt < 4; ++nt)
            acc[mt][nt] = __builtin_amdgcn_mfma_f32_16x16x32_bf16(af[r][mt], Bh[r][nt],
                                                                  acc[mt][nt], 0, 0, 0);
    }

    // ---- dump per-wave partials into double-buffered Gp (D: col=l15, row=quad*4+reg)
    float* __restrict__ Gp = Gp_s + (t & 1) * (4 * 32 * 68);
#pragma unroll
    for (int mt = 0; mt < 2; ++mt)
#pragma unroll
      for (int nt = 0; nt < 4; ++nt)
#pragma unroll
        for (int rr = 0; rr < 4; ++rr)
          Gp[(wv * 32 + mt * 16 + quad * 4 + rr) * 68 + nt * 16 + l15] = acc[mt][nt][rr];
    __syncthreads();   // the ONLY barrier per step

    // ---- elementwise: reduce partials, gates, c/h update, store h
    {
      float pre[4][2];
#pragma unroll
      for (int g = 0; g < 4; ++g) {
        int c = g * 16 + 2 * ecp;
        float s0 = bias2[g][0], s1 = bias2[g][1];
#pragma unroll
        for (int w = 0; w < 4; ++w) {
          s0 += Gp[(w * 32 + erow) * 68 + c];
          s1 += Gp[(w * 32 + erow) * 68 + c + 1];
        }
        pre[g][0] = s0; pre[g][1] = s1;
      }
      float hv[2];
#pragma unroll
      for (int j = 0; j < 2; ++j) {
        float iv = sigm(pre[0][j]);
        float fv = sigm(pre[1][j]);
        float gv = tanh_(pre[2][j]);
        float ov = sigm(pre[3][j]);
        float cn = fv * cst2[j] + iv * gv;
        cst2[j] = cn;
        hv[j] = ov * tanh_(cn);
      }
      unsigned pack = (unsigned)f2b(hv[0]) | ((unsigned)f2b(hv[1]) << 16);
      if constexpr (IS_L0) {
        unsigned* ring32 = (unsigned*)h1ring;
        __hip_atomic_store(&ring32[(size_t)(t & (RING - 1)) * (B_ * H_ / 2) + stoff],
                           pack, AQ, SC);
      } else {
        __hip_atomic_store(&hx32[(size_t)((t + 1) & 1) * (B_ * H_ / 2) + stoff], pack, AQ, SC);
        if (t == T_ - 1) {
          float part = hv[0] * Wfc[hg] + hv[1] * Wfc[hg + 1];
          part += __shfl_down(part, 4, 8);
          part += __shfl_down(part, 2, 8);
          part += __shfl_down(part, 1, 8);
          if (ecp == 0) atomicAdd(&out[bg], part);
        }
      }
    }

    // ---- per-wave drain + single-scatter signal (no barrier)
    asm volatile("s_waitcnt vmcnt(0)" ::: "memory");
    {
      const unsigned v = (unsigned)(t + 1);
      if constexpr (IS_L0) {
        __hip_atomic_store(sigPtr, v, AQ, SC);        // all 64 lanes: 32 rec + 32 input
      } else {
        if (lane < 40) __hip_atomic_store(sigPtr, v, AQ, SC);  // 32 rec + 8 credits
      }
    }
  }
}

__global__ __launch_bounds__(256, 2) void lstm_fused(
    const float* __restrict__ x,
    const u16* __restrict__ wih0, const u16* __restrict__ whh0, const float* __restrict__ b0,
    const u16* __restrict__ wih1, const u16* __restrict__ whh1, const float* __restrict__ b1,
    unsigned* __restrict__ hx1, u16* __restrict__ h1ring,
    const float* __restrict__ Wfc, float* __restrict__ out,
    unsigned* __restrict__ l0c, unsigned* __restrict__ l1c)
{
  __shared__ __align__(16) float Gp_s[2 * 4 * 32 * 68];
  if (blockIdx.x < 256)
    lstm_body<true>(blockIdx.x, x, wih0, whh0, b0, (unsigned*)nullptr, h1ring,
                    (const float*)nullptr, (float*)nullptr, l0c, l1c, Gp_s);
  else
    lstm_body<false>(blockIdx.x - 256, (const float*)nullptr, wih1, whh1, b1, hx1, h1ring,
                     Wfc, out, l0c, l1c, Gp_s);
}

extern "C" void kernel_launch(void* const* d_in, const int* in_sizes, int n_in,
                              void* d_out, int out_size, void* d_ws, size_t ws_size,
                              hipStream_t stream) {
  if (ws_size < (size_t)WS_NEEDED) return;

  const float* x    = (const float*)d_in[0];
  const float* Wih0 = (const float*)d_in[1];
  const float* Whh0 = (const float*)d_in[2];
  const float* bih0 = (const float*)d_in[3];
  const float* bhh0 = (const float*)d_in[4];
  const float* Wih1 = (const float*)d_in[5];
  const float* Whh1 = (const float*)d_in[6];
  const float* bih1 = (const float*)d_in[7];
  const float* bhh1 = (const float*)d_in[8];
  const float* Wfc  = (const float*)d_in[9];
  const float* bfc  = (const float*)d_in[10];

  char* ws = (char*)d_ws;
  unsigned* l0c  = (unsigned*)(ws + OFF_L0C);
  unsigned* l1c  = (unsigned*)(ws + OFF_L1C);
  float* b0      = (float*)(ws + OFF_B0);
  float* b1      = (float*)(ws + OFF_B1);
  u16* wih0b     = (u16*)(ws + OFF_WIH0);
  u16* whh0b     = (u16*)(ws + OFF_WHH0);
  u16* wih1b     = (u16*)(ws + OFF_WIH1);
  u16* whh1b     = (u16*)(ws + OFF_WHH1);
  unsigned* hx1  = (unsigned*)(ws + OFF_HX1);
  u16* h1ring    = (u16*)(ws + OFF_H1R);
  float* out     = (float*)d_out;

  // prep: 131072 + 256 + 2048*2 + 131072 + 3*1048576 = 3,412,224 elements = 13329 blocks
  prep_kernel<<<13329, 256, 0, stream>>>(Wih0, Whh0, bih0, bhh0, Wih1, Whh1, bih1, bhh1,
                                         bfc, out, ws);

  lstm_fused<<<512, 256, 0, stream>>>(x, wih0b, whh0b, b0, wih1b, whh1b, b1,
                                      hx1, h1ring, Wfc, out, l0c, l1c);
}

// Round 4
// 2848.342 us; speedup vs baseline: 1.6683x; 1.3467x over previous
//
#include <hip/hip_runtime.h>

typedef unsigned short u16;
typedef unsigned long long u64;
typedef short bf16x8 __attribute__((ext_vector_type(8)));
typedef float f32x4 __attribute__((ext_vector_type(4)));

#define B_ 256
#define T_ 512
#define I_ 64
#define H_ 512
#define RING 32

// ---------------- ws layout (bytes) ----------------
// R0-proven mailboxes: per-CONSUMER 128B lines of 32 block-granular slots.
//   F0: L0 recurrent (L0 wave0 polls slots=producer jn'; L0 wave0 stores after barrier)
//   F1: L0->L1 h1-ready (L0 stores, L1 polls)
//   F2: L1 recurrent
//   F3: L1->L0 ring-consumed credits (L1 stores, L0 polls)
// h1 ring is the ONLY L0 h buffer: L0 rec reads slot (t-1)&31, L1 reads slot t&31.
// Ring layout A-fragment-coalesced: [slot][k8=k/8][row 0..255][8 k-elems] bf16.
#define OFF_F0    0u
#define OFF_F1    32768u
#define OFF_F2    65536u
#define OFF_F3    98304u
#define OFF_B0    131072u      // 2048 f32
#define OFF_B1    139264u      // 2048 f32
#define OFF_WIH0  147456u      // 2048x64 bf16
#define OFF_WHH0  409600u      // 2048x512 bf16
#define OFF_WIH1  2506752u     // 2048x512 bf16
#define OFF_WHH1  4603904u     // 2048x512 bf16
#define OFF_HX1   6701056u     // 2 x [64][256][8] bf16 (L1 own recurrent, parity)
#define OFF_H1R   7225344u     // RING x [64][256][8] bf16 ring
#define WS_NEEDED 15613952u

#define AQ __ATOMIC_RELAXED
#define SC __HIP_MEMORY_SCOPE_AGENT

static __device__ __forceinline__ u16 f2b(float f) {
  union { float f; unsigned u; } v; v.f = f;
  unsigned r = (v.u + 0x7FFFu + ((v.u >> 16) & 1u)) >> 16;
  return (u16)r;
}
static __device__ __forceinline__ float sigm(float x) { return 1.f / (1.f + __expf(-x)); }
static __device__ __forceinline__ float tanh_(float x) { return 1.f - 2.f / (__expf(2.f * x) + 1.f); }

// ---------------- prep: bf16 weights, bias sums, flag zero, out=bfc ----------------
__global__ void prep_kernel(const float* __restrict__ Wih0, const float* __restrict__ Whh0,
                            const float* __restrict__ bih0, const float* __restrict__ bhh0,
                            const float* __restrict__ Wih1, const float* __restrict__ Whh1,
                            const float* __restrict__ bih1, const float* __restrict__ bhh1,
                            const float* __restrict__ bfc, float* __restrict__ out,
                            char* __restrict__ ws) {
  unsigned* flags = (unsigned*)(ws + OFF_F0);  // F0..F3 contiguous: 32768 u32
  float* b0 = (float*)(ws + OFF_B0);
  float* b1 = (float*)(ws + OFF_B1);
  u16* wih0b = (u16*)(ws + OFF_WIH0);
  u16* whh0b = (u16*)(ws + OFF_WHH0);
  u16* wih1b = (u16*)(ws + OFF_WIH1);
  u16* whh1b = (u16*)(ws + OFF_WHH1);

  long long i = (long long)blockIdx.x * 256 + threadIdx.x;
  if (i < 32768) { __hip_atomic_store(&flags[i], 0u, AQ, SC); return; }
  i -= 32768;
  if (i < 256) { out[i] = bfc[0]; return; }   // FC bias; L1 atomicAdds partials
  i -= 256;
  if (i < 2048) { b0[i] = bih0[i] + bhh0[i]; return; }
  i -= 2048;
  if (i < 2048) { b1[i] = bih1[i] + bhh1[i]; return; }
  i -= 2048;
  if (i < 131072) { wih0b[i] = f2b(Wih0[i]); return; }
  i -= 131072;
  if (i < 1048576) { whh0b[i] = f2b(Whh0[i]); return; }
  i -= 1048576;
  if (i < 1048576) { wih1b[i] = f2b(Wih1[i]); return; }
  i -= 1048576;
  if (i < 1048576) { whh1b[i] = f2b(Whh1[i]); return; }
}

// ---------------- fused 2-layer pipelined LSTM ----------------
// 512 blocks co-resident (2/CU): 0-255 = layer0, 256-511 = layer1 (lag 1 step).
// Block (ib=bx>>5, jn=bx&31): 32 batch rows x 16 h-cols; 4 waves K-split; Whh in regs.
// Per step (3 barriers, R0 contention profile):
//   [input GEMM from regs] -> wave0 poll -> bar#1 -> rec GEMM -> dump -> bar#2 ->
//   elemwise + h store -> bar#3 (drains stores) -> wave0 signal (block-granular flags).
template <bool IS_L0>
__device__ __forceinline__ void lstm_body(
    int bx,
    const float* __restrict__ x,      // L0: [B,T,64]
    const u16* __restrict__ Wib,      // bf16: L0 [2048][64], L1 [2048][512]
    const u16* __restrict__ Whb,      // bf16 [2048][512]
    const float* __restrict__ bias,   // [2048]
    unsigned* __restrict__ hx32,      // L1 only: own recurrent parity buffer (u32 view)
    u16* __restrict__ h1ring,         // ring [RING][64][256][8] bf16
    const float* __restrict__ Wfc, float* __restrict__ out,
    unsigned* __restrict__ fR,        // own recurrent mailbox
    unsigned* __restrict__ fP,        // h1-ready (L0 stores, L1 polls)
    unsigned* __restrict__ fC,        // ring credits (L1 stores, L0 polls)
    float* __restrict__ Gp_s)         // [4*32][68] partial-sum buffer
{
  const int tid = threadIdx.x;
  const int wv = tid >> 6;
  const int lane = tid & 63;
  const int quad = lane >> 4;
  const int l15 = lane & 15;
  const int jn = bx & 31;
  const int ib = bx >> 5;

  // ---- preload B fragments (lane: n=l15, k=quad*8+j); wave owns ksteps wv*4..wv*4+3
  bf16x8 Bh[4][4];
#pragma unroll
  for (int r = 0; r < 4; ++r)
#pragma unroll
    for (int nt = 0; nt < 4; ++nt)
      Bh[r][nt] = *(const bf16x8*)&Whb[(size_t)(nt * 512 + jn * 16 + l15) * 512 +
                                       (wv * 4 + r) * 32 + quad * 8];
  bf16x8 Bx[4][4];  // L1 input weights (full K=512 split)
  bf16x8 Bx0[4];    // L0 input weights (waves 0,1; K-half = wv)
  if constexpr (IS_L0) {
    if (wv < 2) {
#pragma unroll
      for (int nt = 0; nt < 4; ++nt)
        Bx0[nt] = *(const bf16x8*)&Wib[(size_t)(nt * 512 + jn * 16 + l15) * 64 +
                                       wv * 32 + quad * 8];
    }
  } else {
#pragma unroll
    for (int r = 0; r < 4; ++r)
#pragma unroll
      for (int nt = 0; nt < 4; ++nt)
        Bx[r][nt] = *(const bf16x8*)&Wib[(size_t)(nt * 512 + jn * 16 + l15) * 512 +
                                         (wv * 4 + r) * 32 + quad * 8];
  }

  const int erow = tid >> 3;     // elementwise: batch row 0..31
  const int ecp = tid & 7;       // col pair
  float bias2[4][2];
#pragma unroll
  for (int g = 0; g < 4; ++g) {
    bias2[g][0] = bias[g * 512 + jn * 16 + 2 * ecp];
    bias2[g][1] = bias[g * 512 + jn * 16 + 2 * ecp + 1];
  }
  float cst2[2] = {0.f, 0.f};
  const f32x4 zf = {0.f, 0.f, 0.f, 0.f};
  const unsigned lineoff = ((unsigned)ib * 32 + jn) * 32;

  // transposed-layout store offset (u32 units): hg -> k8 = hg>>3, elem pair = ecp&3
  const int bg = ib * 32 + erow;
  const int hg = jn * 16 + 2 * ecp;
  const unsigned stoff = (unsigned)(((hg >> 3) * 256 + bg) * 4 + (ecp & 3));

  for (int t = 0; t < T_; ++t) {
    f32x4 acc[2][4];
#pragma unroll
    for (int mt = 0; mt < 2; ++mt)
#pragma unroll
      for (int nt = 0; nt < 4; ++nt) acc[mt][nt] = zf;

    if constexpr (IS_L0) {
      // x(t) -> registers; input GEMM before the poll (h-independent)
      if (wv < 2) {
        const float* xp = x + ((size_t)(ib * 32 + l15) * T_ + t) * 64 + wv * 32 + quad * 8;
        const float* xq = xp + (size_t)16 * T_ * 64;
        float4 xa = *(const float4*)xp;
        float4 xb = *(const float4*)(xp + 4);
        float4 xc = *(const float4*)xq;
        float4 xd = *(const float4*)(xq + 4);
        union { unsigned u[4]; bf16x8 v; } P0, P1;
        P0.u[0] = (unsigned)f2b(xa.x) | ((unsigned)f2b(xa.y) << 16);
        P0.u[1] = (unsigned)f2b(xa.z) | ((unsigned)f2b(xa.w) << 16);
        P0.u[2] = (unsigned)f2b(xb.x) | ((unsigned)f2b(xb.y) << 16);
        P0.u[3] = (unsigned)f2b(xb.z) | ((unsigned)f2b(xb.w) << 16);
        P1.u[0] = (unsigned)f2b(xc.x) | ((unsigned)f2b(xc.y) << 16);
        P1.u[1] = (unsigned)f2b(xc.z) | ((unsigned)f2b(xc.w) << 16);
        P1.u[2] = (unsigned)f2b(xd.x) | ((unsigned)f2b(xd.y) << 16);
        P1.u[3] = (unsigned)f2b(xd.z) | ((unsigned)f2b(xd.w) << 16);
#pragma unroll
        for (int nt = 0; nt < 4; ++nt) {
          acc[0][nt] = __builtin_amdgcn_mfma_f32_16x16x32_bf16(P0.v, Bx0[nt], acc[0][nt], 0, 0, 0);
          acc[1][nt] = __builtin_amdgcn_mfma_f32_16x16x32_bf16(P1.v, Bx0[nt], acc[1][nt], 0, 0, 0);
        }
      }
      // wave0 poll: lanes<32 rec flags >= t; lanes>=32 ring credits >= t-RING+1
      if (t && wv == 0) {
        unsigned tgtR = (unsigned)t;
        unsigned tgtC = (t >= RING) ? (unsigned)(t - RING + 1) : 0u;
        for (;;) {
          unsigned vv, tg;
          if (lane < 32) { vv = __hip_atomic_load(&fR[lineoff + lane], AQ, SC); tg = tgtR; }
          else           { vv = __hip_atomic_load(&fC[lineoff + lane - 32], AQ, SC); tg = tgtC; }
          if (!__any(vv < tg)) break;
        }
      }
      __syncthreads();   // bar#1: joins poll
    } else {
      // wave0 poll: lanes<32 h1(t) ready (fP >= t+1); lanes>=32 own rec (fR >= t)
      if (wv == 0) {
        unsigned tgtP = (unsigned)(t + 1);
        unsigned tgtR = (unsigned)t;
        for (;;) {
          unsigned vv, tg;
          if (lane < 32) { vv = __hip_atomic_load(&fP[lineoff + lane], AQ, SC); tg = tgtP; }
          else           { vv = __hip_atomic_load(&fR[lineoff + lane - 32], AQ, SC); tg = tgtR; }
          if (!__any(vv < tg)) break;
        }
      }
      __syncthreads();   // bar#1: joins poll
      // input GEMM from ring slot t&(RING-1)
      const u64* hq1 = (const u64*)h1ring + (size_t)(t & (RING - 1)) * (B_ * H_ / 4);
#pragma unroll
      for (int r = 0; r < 4; ++r) {
        int ks = wv * 4 + r;
        bf16x8 af[2];
#pragma unroll
        for (int mt = 0; mt < 2; ++mt) {
          const u64* p = hq1 + (size_t)((ks * 4 + quad) * 256 + ib * 32 + mt * 16 + l15) * 2;
          union { u64 q[2]; bf16x8 v; } u;
          u.q[0] = __hip_atomic_load(p, AQ, SC);
          u.q[1] = __hip_atomic_load(p + 1, AQ, SC);
          af[mt] = u.v;
        }
#pragma unroll
        for (int nt = 0; nt < 4; ++nt) {
          acc[0][nt] = __builtin_amdgcn_mfma_f32_16x16x32_bf16(af[0], Bx[r][nt], acc[0][nt], 0, 0, 0);
          acc[1][nt] = __builtin_amdgcn_mfma_f32_16x16x32_bf16(af[1], Bx[r][nt], acc[1][nt], 0, 0, 0);
        }
      }
    }

    // ---- recurrent GEMM: L0 reads ring slot (t-1)&31, L1 its parity buffer
    if (t) {
      const u64* hq;
      if constexpr (IS_L0)
        hq = (const u64*)h1ring + (size_t)((t - 1) & (RING - 1)) * (B_ * H_ / 4);
      else
        hq = (const u64*)hx32 + (size_t)(t & 1) * (B_ * H_ / 4);
      bf16x8 af[4][2];
#pragma unroll
      for (int r = 0; r < 4; ++r) {
        int ks = wv * 4 + r;
#pragma unroll
        for (int mt = 0; mt < 2; ++mt) {
          const u64* p = hq + (size_t)((ks * 4 + quad) * 256 + ib * 32 + mt * 16 + l15) * 2;
          union { u64 q[2]; bf16x8 v; } u;
          u.q[0] = __hip_atomic_load(p, AQ, SC);
          u.q[1] = __hip_atomic_load(p + 1, AQ, SC);
          af[r][mt] = u.v;
        }
      }
#pragma unroll
      for (int r = 0; r < 4; ++r)
#pragma unroll
        for (int mt = 0; mt < 2; ++mt)
#pragma unroll
          for (int nt = 0; nt < 4; ++nt)
            acc[mt][nt] = __builtin_amdgcn_mfma_f32_16x16x32_bf16(af[r][mt], Bh[r][nt],
                                                                  acc[mt][nt], 0, 0, 0);
    }

    // ---- dump per-wave partials (D: col=l15, row=quad*4+reg)
#pragma unroll
    for (int mt = 0; mt < 2; ++mt)
#pragma unroll
      for (int nt = 0; nt < 4; ++nt)
#pragma unroll
        for (int rr = 0; rr < 4; ++rr)
          Gp_s[(wv * 32 + mt * 16 + quad * 4 + rr) * 68 + nt * 16 + l15] = acc[mt][nt][rr];
    __syncthreads();   // bar#2

    // ---- elementwise: reduce partials, gates, c/h update, store h
    {
      float pre[4][2];
#pragma unroll
      for (int g = 0; g < 4; ++g) {
        int c = g * 16 + 2 * ecp;
        float s0 = bias2[g][0], s1 = bias2[g][1];
#pragma unroll
        for (int w = 0; w < 4; ++w) {
          s0 += Gp_s[(w * 32 + erow) * 68 + c];
          s1 += Gp_s[(w * 32 + erow) * 68 + c + 1];
        }
        pre[g][0] = s0; pre[g][1] = s1;
      }
      float hv[2];
#pragma unroll
      for (int j = 0; j < 2; ++j) {
        float iv = sigm(pre[0][j]);
        float fv = sigm(pre[1][j]);
        float gv = tanh_(pre[2][j]);
        float ov = sigm(pre[3][j]);
        float cn = fv * cst2[j] + iv * gv;
        cst2[j] = cn;
        hv[j] = ov * tanh_(cn);
      }
      unsigned pack = (unsigned)f2b(hv[0]) | ((unsigned)f2b(hv[1]) << 16);
      if constexpr (IS_L0) {
        unsigned* ring32 = (unsigned*)h1ring;
        __hip_atomic_store(&ring32[(size_t)(t & (RING - 1)) * (B_ * H_ / 2) + stoff],
                           pack, AQ, SC);
      } else {
        __hip_atomic_store(&hx32[(size_t)((t + 1) & 1) * (B_ * H_ / 2) + stoff], pack, AQ, SC);
        if (t == T_ - 1) {
          float part = hv[0] * Wfc[hg] + hv[1] * Wfc[hg + 1];
          part += __shfl_down(part, 4, 8);
          part += __shfl_down(part, 2, 8);
          part += __shfl_down(part, 1, 8);
          if (ecp == 0) atomicAdd(&out[bg], part);
        }
      }
    }

    // ---- bar#3 drains all waves' h stores (syncthreads implies vmcnt(0)), then
    //      wave0 scatters block-granular flags (R0-proven signal pattern)
    __syncthreads();
    if (wv == 0) {
      unsigned val = (unsigned)(t + 1);
      if constexpr (IS_L0) {
        if (lane < 32) {
          if (t + 1 < T_)
            __hip_atomic_store(&fR[((unsigned)ib * 32 + lane) * 32 + jn], val, AQ, SC);
        } else {
          __hip_atomic_store(&fP[((unsigned)ib * 32 + (lane - 32)) * 32 + jn], val, AQ, SC);
        }
      } else {
        if (t + 1 < T_) {
          if (lane < 32)
            __hip_atomic_store(&fR[((unsigned)ib * 32 + lane) * 32 + jn], val, AQ, SC);
          else
            __hip_atomic_store(&fC[((unsigned)ib * 32 + (lane - 32)) * 32 + jn], val, AQ, SC);
        }
      }
    }
  }
}

__global__ __launch_bounds__(256, 2) void lstm_fused(
    const float* __restrict__ x,
    const u16* __restrict__ wih0, const u16* __restrict__ whh0, const float* __restrict__ b0,
    const u16* __restrict__ wih1, const u16* __restrict__ whh1, const float* __restrict__ b1,
    unsigned* __restrict__ hx1, u16* __restrict__ h1ring,
    const float* __restrict__ Wfc, float* __restrict__ out,
    unsigned* __restrict__ f0, unsigned* __restrict__ f1, unsigned* __restrict__ f2,
    unsigned* __restrict__ f3)
{
  __shared__ __align__(16) float Gp_s[4 * 32 * 68];
  if (blockIdx.x < 256)
    lstm_body<true>(blockIdx.x, x, wih0, whh0, b0, (unsigned*)nullptr, h1ring,
                    (const float*)nullptr, (float*)nullptr, f0, f1, f3, Gp_s);
  else
    lstm_body<false>(blockIdx.x - 256, (const float*)nullptr, wih1, whh1, b1, hx1, h1ring,
                     Wfc, out, f2, f1, f3, Gp_s);
}

extern "C" void kernel_launch(void* const* d_in, const int* in_sizes, int n_in,
                              void* d_out, int out_size, void* d_ws, size_t ws_size,
                              hipStream_t stream) {
  if (ws_size < (size_t)WS_NEEDED) return;

  const float* x    = (const float*)d_in[0];
  const float* Wih0 = (const float*)d_in[1];
  const float* Whh0 = (const float*)d_in[2];
  const float* bih0 = (const float*)d_in[3];
  const float* bhh0 = (const float*)d_in[4];
  const float* Wih1 = (const float*)d_in[5];
  const float* Whh1 = (const float*)d_in[6];
  const float* bih1 = (const float*)d_in[7];
  const float* bhh1 = (const float*)d_in[8];
  const float* Wfc  = (const float*)d_in[9];
  const float* bfc  = (const float*)d_in[10];

  char* ws = (char*)d_ws;
  unsigned* f0   = (unsigned*)(ws + OFF_F0);
  unsigned* f1   = (unsigned*)(ws + OFF_F1);
  unsigned* f2   = (unsigned*)(ws + OFF_F2);
  unsigned* f3   = (unsigned*)(ws + OFF_F3);
  float* b0      = (float*)(ws + OFF_B0);
  float* b1      = (float*)(ws + OFF_B1);
  u16* wih0b     = (u16*)(ws + OFF_WIH0);
  u16* whh0b     = (u16*)(ws + OFF_WHH0);
  u16* wih1b     = (u16*)(ws + OFF_WIH1);
  u16* whh1b     = (u16*)(ws + OFF_WHH1);
  unsigned* hx1  = (unsigned*)(ws + OFF_HX1);
  u16* h1ring    = (u16*)(ws + OFF_H1R);
  float* out     = (float*)d_out;

  // prep: 32768 + 256 + 2048*2 + 131072 + 3*1048576 = 3,314,560 elements
  prep_kernel<<<12948, 256, 0, stream>>>(Wih0, Whh0, bih0, bhh0, Wih1, Whh1, bih1, bhh1,
                                         bfc, out, ws);

  lstm_fused<<<512, 256, 0, stream>>>(x, wih0b, whh0b, b0, wih1b, whh1b, b1,
                                      hx1, h1ring, Wfc, out, f0, f1, f2, f3);
}